// Round 5
// baseline (618.289 us; speedup 1.0000x reference)
//
#include <hip/hip_runtime.h>

typedef _Float16 f16;
typedef unsigned short u16;
typedef unsigned int u32;
typedef _Float16 f16x8 __attribute__((ext_vector_type(8)));
typedef float f32x4 __attribute__((ext_vector_type(4)));
typedef float f32x16 __attribute__((ext_vector_type(16)));

union F16x8U { f16x8 v; uint4 q; u16 us[8]; f16 h[8]; };
union HBits { f16 f; u16 u; };

#define GLD16(g, l)                                                        \
  __builtin_amdgcn_global_load_lds(                                        \
      (const __attribute__((address_space(1))) void*)(g),                  \
      (__attribute__((address_space(3))) void*)(l), 16, 0, 0)

// ---------------------------------------------------------------- converts
// fused: blocks [0,2048) x-cvt, [2048,2336) wpre, [2336,2408) rw, rest wleaf
__global__ void kcvt_all(const float* __restrict__ x, f16* __restrict__ xo,
                         const float* __restrict__ w, f16* __restrict__ wo,
                         const float* __restrict__ rwsrc, f16* __restrict__ ro,
                         const float* __restrict__ wl, const float* __restrict__ blf,
                         f16* __restrict__ wpk) {
  int b = blockIdx.x;
  if (b < 2048) {                          // x: [8192][512] f32 -> f16
    int i = (b * 256 + threadIdx.x) << 3;
    float4 a = *(const float4*)(x + i);
    float4 c = *(const float4*)(x + i + 4);
    F16x8U u;
    u.h[0] = (f16)a.x; u.h[1] = (f16)a.y; u.h[2] = (f16)a.z; u.h[3] = (f16)a.w;
    u.h[4] = (f16)c.x; u.h[5] = (f16)c.y; u.h[6] = (f16)c.z; u.h[7] = (f16)c.w;
    *(uint4*)(xo + i) = u.q;
  } else if (b < 2336) {                   // W_pre -> [576][512] f16 (pad rows 0)
    int e = ((b - 2048) * 256 + threadIdx.x) << 2;
    int row = e >> 9, col = e & 511;
    union { uint2 q; f16 h[4]; } u;
    if (row < 513) {
      float4 v = *(const float4*)(w + (size_t)row * 512 + col);
      u.h[0] = (f16)v.x; u.h[1] = (f16)v.y; u.h[2] = (f16)v.z; u.h[3] = (f16)v.w;
    } else {
      u.h[0] = u.h[1] = u.h[2] = u.h[3] = (f16)0.0f;
    }
    *(uint2*)(wo + e) = u.q;
  } else if (b < 2408) {                   // right_w -> [128][576] f16
    int e = ((b - 2336) * 256 + threadIdx.x) << 2;
    int row = e / 576, c0 = e - row * 576;
    union { uint2 q; f16 h[4]; } u;
#pragma unroll
    for (int i = 0; i < 4; ++i) {
      int c = c0 + i;
      float v = (row < 127 && c < 513) ? rwsrc[(size_t)row * 513 + c] : 0.0f;
      u.h[i] = (f16)v;
    }
    *(uint2*)(ro + e) = u.q;
  } else {                                 // W_pack [32768][544]: W_leaf|b|0
    int e = ((b - 2408) * 256 + threadIdx.x) << 3;
    int row = e / 544, c0 = e - row * 544;
    const float* src = wl + (size_t)row * 513 + c0;
    F16x8U u;
#pragma unroll
    for (int i = 0; i < 8; ++i) {
      int c = c0 + i;
      float v = (c < 513) ? src[i] : ((c == 513) ? blf[row] : 0.0f);
      u.h[i] = (f16)v;
    }
    *(uint4*)(wpk + e) = u.q;
  }
}

// ---------------------------------------------------- generic 128x64 GEMM-BT
template <int MODE>
__global__ __launch_bounds__(256, 2) void kgemm(
    const f16* __restrict__ A, const f16* __restrict__ B,
    const float* __restrict__ bias, void* __restrict__ C,
    int NK, int astr, int bstr) {
  __shared__ alignas(16) f16 al[2][128 * 32];
  __shared__ alignas(16) f16 bl[2][64 * 40];
  const int tid = threadIdx.x, lane = tid & 63, wid = tid >> 6;
  const int wm = wid >> 1, wn = wid & 1;
  const int brow = blockIdx.x << 7, bcol = blockIdx.y << 6;

  int arow[2], aseg[2];
#pragma unroll
  for (int i = 0; i < 2; ++i) { int c = i * 256 + tid; arow[i] = c >> 2; aseg[i] = c & 3; }
  int br0 = tid / 5, bs0 = tid - br0 * 5;
  int c1 = 256 + lane;
  int br1 = c1 / 5, bs1 = c1 - br1 * 5;

  f32x4 acc[4][2];
#pragma unroll
  for (int mf = 0; mf < 4; ++mf)
#pragma unroll
    for (int nf = 0; nf < 2; ++nf)
#pragma unroll
      for (int j = 0; j < 4; ++j) acc[mf][nf][j] = 0.0f;

  auto stage = [&](int kc, int bf) {
    int kcol = kc << 5;
#pragma unroll
    for (int i = 0; i < 2; ++i) {
      f16* ldsb = &al[bf][(i * 256 + (wid << 6)) << 3];
      GLD16(A + (size_t)(brow + arow[i]) * astr + kcol + (aseg[i] << 3), ldsb);
    }
    {
      f16* ldsb = &bl[bf][(wid << 6) << 3];
      GLD16(B + (size_t)(bcol + br0) * bstr + kcol + (bs0 < 4 ? (bs0 << 3) : 0), ldsb);
    }
    if (wid == 0) {
      f16* ldsb = &bl[bf][256 << 3];
      GLD16(B + (size_t)(bcol + br1) * bstr + kcol + (bs1 < 4 ? (bs1 << 3) : 0), ldsb);
    }
  };

  stage(0, 0);
  __syncthreads();
  int cur = 0;
  for (int kc = 0; kc < NK; ++kc) {
    if (kc + 1 < NK) stage(kc + 1, cur ^ 1);
    f16x8 af[4], bfm[2];
#pragma unroll
    for (int mf = 0; mf < 4; ++mf)
      af[mf] = *(const f16x8*)&al[cur][((wm << 6) + (mf << 4) + (lane & 15)) * 32 + ((lane >> 4) << 3)];
#pragma unroll
    for (int nf = 0; nf < 2; ++nf)
      bfm[nf] = *(const f16x8*)&bl[cur][((wn << 5) + (nf << 4) + (lane & 15)) * 40 + ((lane >> 4) << 3)];
#pragma unroll
    for (int mf = 0; mf < 4; ++mf)
#pragma unroll
      for (int nf = 0; nf < 2; ++nf)
        acc[mf][nf] = __builtin_amdgcn_mfma_f32_16x16x32_f16(af[mf], bfm[nf], acc[mf][nf], 0, 0, 0);
    __syncthreads();
    cur ^= 1;
  }

#pragma unroll
  for (int mf = 0; mf < 4; ++mf) {
#pragma unroll
    for (int nf = 0; nf < 2; ++nf) {
      int gcol = bcol + (wn << 5) + (nf << 4) + (lane & 15);
      int gr0 = brow + (wm << 6) + (mf << 4) + ((lane >> 4) << 2);
      if (MODE == 0) {
        float bv = (gcol < 513) ? bias[gcol] : 0.0f;
#pragma unroll
        for (int j = 0; j < 4; ++j) {
          float v = fmaxf(acc[mf][nf][j] + bv, 0.0f);
          ((f16*)C)[(size_t)(gr0 + j) * 576 + gcol] = (gcol == 513) ? (f16)1.0f : (f16)v;
        }
      } else {
#pragma unroll
        for (int j = 0; j < 4; ++j)
          ((float*)C)[(size_t)(gr0 + j) * 128 + gcol] = acc[mf][nf][j];
      }
    }
  }
}

// ---------------------------------------------------------------- norms
__global__ void khnorm(const f16* __restrict__ hf, float* __restrict__ ihn) {
  int row = (blockIdx.x << 2) + (threadIdx.x >> 6);
  int lane = threadIdx.x & 63;
  float s = 0.0f;
  for (int c = lane; c < 513; c += 64) {
    float v = (float)hf[(size_t)row * 576 + c];
    s += v * v;
  }
  for (int o = 32; o; o >>= 1) s += __shfl_down(s, o);
  if (!lane) ihn[row] = 1.0f / fmaxf(sqrtf(s), 1e-12f);
}

__global__ void kinvrw(const float* __restrict__ rw, float* __restrict__ irw) {
  int j = (blockIdx.x << 2) + (threadIdx.x >> 6);
  if (j >= 127) return;
  int lane = threadIdx.x & 63;
  float s = 0.0f;
  for (int d = lane; d < 513; d += 64) {
    float v = rw[(size_t)j * 513 + d];
    s += v * v;
  }
  for (int o = 32; o; o >>= 1) s += __shfl_down(s, o);
  if (!lane) irw[j] = 1.0f / fmaxf(sqrtf(s), 1e-12f);
}

// ------------------------------------------------------------- routing/softmax
// s_w layout (u16): idx = l*8192 + (b&~127) + ((b&31)>>1)*8 + (b&1)*4 + ((b>>5)&3)
// DFS over leaves — each tree edge evaluated exactly once.
__global__ void kroute(const float* __restrict__ G, const float* __restrict__ ihn,
                       const float* __restrict__ irw, u16* __restrict__ swh,
                       float* __restrict__ entp) {
  int b = blockIdx.x * 128 + threadIdx.x;
  float ih = ihn[b];
  const float* g = G + (size_t)b * 128;
  float ent = 0.0f;
  size_t wbase = (size_t)(b & ~127) + (((b & 31) >> 1) << 3) + ((b & 1) << 2) + ((b >> 5) & 3);
  float lp[8]; int nd[8];
  nd[0] = 0; lp[0] = 0.0f;
  for (int l = 0; l < 128; ++l) {
    int d0 = l ? (6 - __builtin_ctz(l)) : 0;   // uniform across the wave
#pragma unroll
    for (int d = 0; d < 7; ++d) {
      if (d >= d0) {
        int n = nd[d];
        int bit = (l >> (6 - d)) & 1;
        float cs = g[n] * ih * irw[n];
        float pr = bit ? 0.5f * (1.0f - cs) : 0.5f * (1.0f + cs);
        pr = fminf(fmaxf(pr, 0.01f), 0.99f);
        lp[d + 1] = lp[d] + __logf(pr);
        nd[d + 1] = 2 * n + 1 + bit;
      }
    }
    float sw = __expf(lp[7]);
    ent -= sw * lp[7];
    HBits hb; hb.f = (f16)sw;
    swh[(size_t)l * 8192 + wbase] = hb.u;
  }
  for (int o = 32; o; o >>= 1) ent += __shfl_down(ent, o);
  __shared__ float red[2];
  if (!(threadIdx.x & 63)) red[threadIdx.x >> 6] = ent;
  __syncthreads();
  if (!threadIdx.x) atomicAdd(entp, red[0] + red[1]);
}

// ------------------------------------------------------------------ big GEMM
// out[b,o] = scale * sum_l sum_k (s_w[l,b]*h[b,k]) * Wpack[l*256+o, k]
// v5: BARRIER-FREE K-loop. B tiles are wave-private (each wave stages & reads
// only its own leaves) -> per-wave counted vmcnt(2) is the full sync. A tile
// self-loaded redundantly by every wave (dup LDS writes of identical data),
// double-buffered, one s_barrier per k-chunk (33 total) bounds wave drift.
// 1-step register pre-read hides LDS latency under previous step's MFMA.
// LDS: 32K s_w | 5x8K B ring | 2x4K A = 80KB -> 2 blocks/CU.
__global__ __launch_bounds__(512, 4) void kbig(
    const f16* __restrict__ hf, const f16* __restrict__ wp,
    const u16* __restrict__ swh, const float* __restrict__ entp,
    float* __restrict__ out) {
  __shared__ alignas(16) char smem[81920];

  const int tid = threadIdx.x, lane = tid & 63, wid = tid >> 6;
  const int obl = blockIdx.x & 7, mb = blockIdx.x >> 3;  // obl = XCD id
  const int brow = mb << 7, ocol = obl << 5;

  auto stageA = [&](int kcp) {  // every wave loads the FULL A tile (dup-write)
    const int buf = kcp & 1;
#pragma unroll
    for (int seg = 0; seg < 4; ++seg) {
      int c = seg * 64 + lane, q = c >> 7, row = c & 127;
      GLD16(hf + (size_t)(brow + row) * 576 + kcp * 16 + q * 8,
            smem + 73728 + (buf << 12) + (seg << 10));
    }
  };
  auto stageB = [&](int s) {    // wave stages its own leaf's B rows
    int lgp = s & 15, kcp = s >> 4, slot = s % 5;
    GLD16(wp + (size_t)((lgp * 8 + wid) * 256 + ocol + (lane & 31)) * 544 +
              kcp * 16 + ((lane >> 5) & 1) * 8,
          smem + 32768 + slot * 8192 + (wid << 10));
  };
  auto rdSW = [&](int s) -> uint2 {
    return *(const uint2*)(smem + ((s & 15) * 8 + wid) * 256 + ((lane & 31) << 3));
  };
  auto rdB = [&](int s) -> f16x8 {
    return *(const f16x8*)(smem + 32768 + (s % 5) * 8192 + (wid << 10) +
                           ((lane >> 5) << 9) + ((lane & 31) << 4));
  };

  // ---- prologue: s_w slab (cross-wave, read-only after barrier), A(0), B 0..3
#pragma unroll
  for (int i = 0; i < 4; ++i) {
    int c = i * 512 + tid;
    GLD16(swh + (size_t)(c >> 4) * 8192 + mb * 128 + (c & 15) * 8,
          smem + ((i * 512 + (wid << 6)) << 4));
  }
  stageA(0);
  stageB(0); stageB(1); stageB(2); stageB(3);
  asm volatile("s_waitcnt vmcnt(0)" ::: "memory");
  __builtin_amdgcn_sched_barrier(0);
  __builtin_amdgcn_s_barrier();

  f32x16 acc[4];
#pragma unroll
  for (int mf = 0; mf < 4; ++mf)
#pragma unroll
    for (int j = 0; j < 16; ++j) acc[mf][j] = 0.0f;

  f16x8 afr[4];
  uint2 swP = rdSW(0);
  f16x8 bfP = rdB(0);

  auto cluster = [&](uint2 swq, f16x8 bf) {
    const u16* sc = (const u16*)&swq;
    __builtin_amdgcn_s_setprio(1);
#pragma unroll
    for (int mf = 0; mf < 4; ++mf) {
      HBits hb; hb.u = sc[mf];
      f16x8 as = afr[mf] * hb.f;  // fold s_w[l,row] into A fragment
      acc[mf] = __builtin_amdgcn_mfma_f32_32x32x16_f16(as, bf, acc[mf], 0, 0, 0);
    }
    __builtin_amdgcn_s_setprio(0);
  };

  // ---- main loop: 33 k-chunks x 8 periods; period = steps {2p, 2p+1}
  for (int kc8 = 0; kc8 < 33; ++kc8) {
#pragma unroll
    for (int pp = 0; pp < 8; ++pp) {
      const int p = kc8 * 8 + pp, s0 = 2 * p;
      if (!(kc8 == 32 && pp >= 6)) { stageB(s0 + 4); stageB(s0 + 5); }
      if (pp == 4 && kc8 < 32) {
        __builtin_amdgcn_s_barrier();   // once per k-chunk: A dbuf drift bound
        stageA(kc8 + 1);
      }
      if (kc8 == 32 && pp == 6)      asm volatile("s_waitcnt vmcnt(1)" ::: "memory");
      else if (kc8 == 32 && pp == 7) asm volatile("s_waitcnt vmcnt(0)" ::: "memory");
      else if ((pp == 4 || pp == 5) && kc8 < 32)
                                     asm volatile("s_waitcnt vmcnt(6)" ::: "memory");
      else                           asm volatile("s_waitcnt vmcnt(2)" ::: "memory");
      __builtin_amdgcn_sched_barrier(0);
      if (pp == 0) {  // A fragments for this k-chunk (regs, reused 8 periods)
#pragma unroll
        for (int mf = 0; mf < 4; ++mf)
          afr[mf] = *(const f16x8*)(smem + 73728 + ((kc8 & 1) << 12) +
                                    ((lane >> 5) << 11) + (mf << 9) + ((lane & 31) << 4));
      }
      uint2 swC = rdSW(s0 + 1);       // same-period 2nd step (latency under MFMA)
      f16x8 bfC = rdB(s0 + 1);
      cluster(swP, bfP);
      cluster(swC, bfC);
      if (p < 263) {                  // pre-read next period's 1st step
        swP = rdSW(s0 + 2);
        bfP = rdB(s0 + 2);
      }
    }
  }

  // ---- epilogue: 3-round tree reduction over 8 leaf-partials
  __syncthreads();
  auto writeAcc = [&](char* base) {
#pragma unroll
    for (int mf = 0; mf < 4; ++mf)
#pragma unroll
      for (int rq = 0; rq < 4; ++rq)
        *(f32x4*)(base + ((((mf << 2) + rq) << 6) + lane) * 16) =
            ((const f32x4*)&acc[mf])[rq];
  };
  auto addAcc = [&](const char* base) {
#pragma unroll
    for (int mf = 0; mf < 4; ++mf)
#pragma unroll
      for (int rq = 0; rq < 4; ++rq) {
        f32x4 v = *(const f32x4*)(base + ((((mf << 2) + rq) << 6) + lane) * 16);
        ((f32x4*)&acc[mf])[rq] += v;
      }
  };
  if (wid >= 4) writeAcc(smem + ((wid - 4) << 14));
  __syncthreads();
  if (wid < 4) addAcc(smem + (wid << 14));
  __syncthreads();
  if (wid == 2 || wid == 3) writeAcc(smem + ((wid - 2) << 14));
  __syncthreads();
  if (wid < 2) addAcc(smem + (wid << 14));
  __syncthreads();
  if (wid == 1) writeAcc(smem);
  __syncthreads();
  if (wid == 0) {
    addAcc(smem);
    float scale = 1.0f + (*entp) / (8192.0f * (128.0f / 6.0f) * logf(6.0f));
#pragma unroll
    for (int mf = 0; mf < 4; ++mf)
#pragma unroll
      for (int r = 0; r < 16; ++r) {
        int row = brow + (mf << 5) + (r & 3) + ((r >> 2) << 3) + ((lane >> 5) << 2);
        out[(size_t)row * 256 + ocol + (lane & 31)] = scale * acc[mf][r];
      }
  }
}

// ------------------------------------------------------------------- launch
extern "C" void kernel_launch(void* const* d_in, const int* in_sizes, int n_in,
                              void* d_out, int out_size, void* d_ws, size_t ws_size,
                              hipStream_t stream) {
  const float* x     = (const float*)d_in[0];
  const float* wpre  = (const float*)d_in[1];
  const float* bpre  = (const float*)d_in[2];
  const float* rw    = (const float*)d_in[3];
  const float* wleaf = (const float*)d_in[4];
  const float* bleaf = (const float*)d_in[5];
  float* out = (float*)d_out;

  char* ws = (char*)d_ws;
  constexpr size_t O_ENT = 0;
  constexpr size_t O_XO  = 256;                     // x fp16 [8192][512]
  constexpr size_t O_WPO = O_XO  + 8388608;         // Wpre fp16 [576][512]
  constexpr size_t O_RWO = O_WPO + 589824;          // rw fp16 [128][576]
  constexpr size_t O_IRW = O_RWO + 147456;          // 1/||rw|| [128]
  constexpr size_t O_HO  = O_IRW + 512;             // h fp16 [8192][576]
  constexpr size_t O_IHN = O_HO  + 9437184;         // 1/||h|| [8192]
  constexpr size_t O_G   = O_IHN + 32768;           // G f32 [8192][128]
  constexpr size_t O_SWH = O_G   + 4194304;         // s_w fp16 perm [128][8192]
  constexpr size_t O_WPK = O_SWH + 2097152;         // Wpack fp16 [32768][544]

  float* ent = (float*)(ws + O_ENT);
  f16* xo   = (f16*)(ws + O_XO);
  f16* wpo  = (f16*)(ws + O_WPO);
  f16* rwo  = (f16*)(ws + O_RWO);
  float* irw = (float*)(ws + O_IRW);
  f16* ho   = (f16*)(ws + O_HO);
  float* ihn = (float*)(ws + O_IHN);
  float* go = (float*)(ws + O_G);
  u16* swh  = (u16*)(ws + O_SWH);
  f16* wpk  = (f16*)(ws + O_WPK);

  hipMemsetAsync(ent, 0, sizeof(float), stream);
  kcvt_all<<<11112, 256, 0, stream>>>(x, xo, wpre, wpo, rw, rwo, wleaf, bleaf, wpk);
  kgemm<0><<<dim3(64, 9), 256, 0, stream>>>(xo, wpo, bpre, (void*)ho, 16, 512, 512);
  khnorm<<<2048, 256, 0, stream>>>(ho, ihn);
  kinvrw<<<32, 256, 0, stream>>>(rw, irw);
  kgemm<1><<<dim3(64, 2), 256, 0, stream>>>(ho, rwo, nullptr, (void*)go, 17, 576, 576);
  kroute<<<64, 128, 0, stream>>>(go, ihn, irw, swh, ent);
  kbig<<<512, 512, 0, stream>>>(ho, wpk, swh, ent, out);
}